// Round 1
// baseline (1404.527 us; speedup 1.0000x reference)
//
#include <hip/hip_runtime.h>
#include <hip/hip_bf16.h>

#define NN 100000
#define NE 1600000

typedef __attribute__((ext_vector_type(8))) short bf16x8;
typedef __attribute__((ext_vector_type(4))) float f32x4;

__device__ __forceinline__ unsigned short f2bf(float f) {
    union { float f; unsigned int u; } v; v.f = f;
    unsigned int u = v.u + 0x7fff + ((v.u >> 16) & 1);
    return (unsigned short)(u >> 16);
}
__device__ __forceinline__ float bf2f(unsigned short h) {
    union { unsigned int u; float f; } v; v.u = ((unsigned int)h) << 16;
    return v.f;
}
__device__ __forceinline__ float silu_f(float v) {
    return v / (1.0f + __expf(-v));
}

// ---------------------------------------------------------------------------
// Edge kernel: per 64-edge tile, fused 3-GEMM MLP chain + atomic scatter.
// wave w handles rows 16w..16w+15; MFMA 16x16x32 bf16.
// A-layout: A[m=lane&15][k=quad*8+j]; B-layout: B[k=quad*8+j][n=lane&15];
// C/D: col=lane&15, row=quad*4+reg  (m89/m120-verified mappings)
// ---------------------------------------------------------------------------
__global__ __launch_bounds__(256, 2) void edge_kernel(
    const float* __restrict__ xcur,
    const unsigned short* __restrict__ hbf,
    const int* __restrict__ src,
    const int* __restrict__ dst,
    const float* __restrict__ ew1,   // [129,64]
    const float* __restrict__ eb1,
    const float* __restrict__ ew2,   // [64,64]
    const float* __restrict__ eb2,
    const float* __restrict__ cw1,   // [64,64]
    const float* __restrict__ cb1,
    const float* __restrict__ cw2,   // [64]
    float* __restrict__ h_neigh,     // [N,64]
    float* __restrict__ x_sum)       // [N,3]
{
    __shared__ __align__(16) unsigned short w1T[64 * 128]; // B^T for GEMM1
    __shared__ __align__(16) unsigned short w2T[64 * 64];
    __shared__ __align__(16) unsigned short c1T[64 * 64];
    __shared__ __align__(16) unsigned short fA[64 * 128];  // A-tile; later tA|tB
    __shared__ float eb1s[64], eb2s[64], cb1s[64], cw2s[64], w1l[64];
    __shared__ float xds[64 * 3], rads[64];
    __shared__ int dstL[64];

    const int tid  = threadIdx.x;
    const int wave = tid >> 6;
    const int lane = tid & 63;
    const int quad = lane >> 4;
    const int l15  = lane & 15;

    // stage weights (transposed, bf16) once per block
    for (int i = tid; i < 64 * 128; i += 256) {
        int n = i >> 7, k = i & 127;
        w1T[i] = f2bf(ew1[k * 64 + n]);
    }
    for (int i = tid; i < 64 * 64; i += 256) {
        int n = i >> 6, k = i & 63;
        w2T[i] = f2bf(ew2[k * 64 + n]);
        c1T[i] = f2bf(cw1[k * 64 + n]);
    }
    if (tid < 64) {
        eb1s[tid] = eb1[tid]; eb2s[tid] = eb2[tid]; cb1s[tid] = cb1[tid];
        cw2s[tid] = cw2[tid]; w1l[tid] = ew1[128 * 64 + tid];
    }
    __syncthreads();

    // preload all B fragments into registers (reused across all tiles)
    bf16x8 b1[4][4], b2[2][4], b3[2][4];
#pragma unroll
    for (int nt = 0; nt < 4; ++nt) {
#pragma unroll
        for (int ks = 0; ks < 4; ++ks)
            b1[ks][nt] = *(const bf16x8*)&w1T[(nt * 16 + l15) * 128 + ks * 32 + quad * 8];
#pragma unroll
        for (int ks = 0; ks < 2; ++ks) {
            b2[ks][nt] = *(const bf16x8*)&w2T[(nt * 16 + l15) * 64 + ks * 32 + quad * 8];
            b3[ks][nt] = *(const bf16x8*)&c1T[(nt * 16 + l15) * 64 + ks * 32 + quad * 8];
        }
    }

    for (int t = blockIdx.x; t < NE / 64; t += gridDim.x) {
        __syncthreads();  // protect restaging vs previous iteration's reads
        const int e0 = t * 64;
        {   // gather h[src] | h[dst] into fA (4 threads per edge, 32 bf16 each)
            int e = tid >> 2, part = tid & 3;
            int eg = e0 + e;
            int node = (part < 2) ? src[eg] : dst[eg];
            const uint4* s = (const uint4*)(hbf + node * 64 + (part & 1) * 32);
            uint4* d = (uint4*)(fA + e * 128 + part * 32);
            d[0] = s[0]; d[1] = s[1]; d[2] = s[2]; d[3] = s[3];
        }
        if (tid < 64) {  // radial + normalized x_diff (fp32)
            int eg = e0 + tid;
            int sn = src[eg], dn = dst[eg];
            float dx = xcur[sn * 3 + 0] - xcur[dn * 3 + 0];
            float dy = xcur[sn * 3 + 1] - xcur[dn * 3 + 1];
            float dz = xcur[sn * 3 + 2] - xcur[dn * 3 + 2];
            float rad = dx * dx + dy * dy + dz * dz;
            float inv = 1.0f / (sqrtf(rad) + 1e-30f);
            xds[tid * 3 + 0] = dx * inv;
            xds[tid * 3 + 1] = dy * inv;
            xds[tid * 3 + 2] = dz * inv;
            rads[tid] = rad;
            dstL[tid] = dn;
        }
        __syncthreads();

        // ---- GEMM1: f[:,0:128] @ W1[0:128,:], K=128
        f32x4 acc[4];
#pragma unroll
        for (int nt = 0; nt < 4; ++nt) acc[nt] = (f32x4){0.f, 0.f, 0.f, 0.f};
        const unsigned short* aBase = &fA[(wave * 16 + l15) * 128 + quad * 8];
#pragma unroll
        for (int ks = 0; ks < 4; ++ks) {
            bf16x8 a = *(const bf16x8*)(aBase + ks * 32);
#pragma unroll
            for (int nt = 0; nt < 4; ++nt)
                acc[nt] = __builtin_amdgcn_mfma_f32_16x16x32_bf16(a, b1[ks][nt], acc[nt], 0, 0, 0);
        }
        __syncthreads();  // fA (as f) dead; tA/tB alias it

        unsigned short* tA = fA;            // [64][64]
        unsigned short* tB = fA + 64 * 64;  // [64][64]
        // epilogue: + bias + radial rank-1 (fp32) + silu -> tA (bf16)
#pragma unroll
        for (int nt = 0; nt < 4; ++nt) {
            int col = nt * 16 + l15;
#pragma unroll
            for (int r = 0; r < 4; ++r) {
                int erow = wave * 16 + quad * 4 + r;
                float v = acc[nt][r] + eb1s[col] + rads[erow] * w1l[col];
                tA[erow * 64 + col] = f2bf(silu_f(v));
            }
        }
        // ---- GEMM2: t1 @ W2, K=64 (wave-local rows, no barrier needed)
        f32x4 acc2[4];
#pragma unroll
        for (int nt = 0; nt < 4; ++nt) acc2[nt] = (f32x4){0.f, 0.f, 0.f, 0.f};
        const unsigned short* aB2 = &tA[(wave * 16 + l15) * 64 + quad * 8];
#pragma unroll
        for (int ks = 0; ks < 2; ++ks) {
            bf16x8 a = *(const bf16x8*)(aB2 + ks * 32);
#pragma unroll
            for (int nt = 0; nt < 4; ++nt)
                acc2[nt] = __builtin_amdgcn_mfma_f32_16x16x32_bf16(a, b2[ks][nt], acc2[nt], 0, 0, 0);
        }
        // epilogue: silu -> msg_h; atomic scatter + tB (bf16)
#pragma unroll
        for (int nt = 0; nt < 4; ++nt) {
            int col = nt * 16 + l15;
#pragma unroll
            for (int r = 0; r < 4; ++r) {
                int erow = wave * 16 + quad * 4 + r;
                float v = silu_f(acc2[nt][r] + eb2s[col]);
                atomicAdd(&h_neigh[dstL[erow] * 64 + col], v);
                tB[erow * 64 + col] = f2bf(v);
            }
        }
        // ---- GEMM3: msg_h @ CW1, K=64
        f32x4 acc3[4];
#pragma unroll
        for (int nt = 0; nt < 4; ++nt) acc3[nt] = (f32x4){0.f, 0.f, 0.f, 0.f};
        const unsigned short* aB3 = &tB[(wave * 16 + l15) * 64 + quad * 8];
#pragma unroll
        for (int ks = 0; ks < 2; ++ks) {
            bf16x8 a = *(const bf16x8*)(aB3 + ks * 32);
#pragma unroll
            for (int nt = 0; nt < 4; ++nt)
                acc3[nt] = __builtin_amdgcn_mfma_f32_16x16x32_bf16(a, b3[ks][nt], acc3[nt], 0, 0, 0);
        }
        // coord head: silu, dot with cw2 (fp32), 16-lane reduce, scatter msg_x
        float part_[4] = {0.f, 0.f, 0.f, 0.f};
#pragma unroll
        for (int nt = 0; nt < 4; ++nt) {
            int col = nt * 16 + l15;
#pragma unroll
            for (int r = 0; r < 4; ++r) {
                float v = silu_f(acc3[nt][r] + cb1s[col]);
                part_[r] += v * cw2s[col];
            }
        }
#pragma unroll
        for (int r = 0; r < 4; ++r) {
            float p = part_[r];
            p += __shfl_xor(p, 1);
            p += __shfl_xor(p, 2);
            p += __shfl_xor(p, 4);
            p += __shfl_xor(p, 8);
            part_[r] = p;
        }
        if (l15 < 3) {
#pragma unroll
            for (int r = 0; r < 4; ++r) {
                int erow = wave * 16 + quad * 4 + r;
                atomicAdd(&x_sum[dstL[erow] * 3 + l15], part_[r] * xds[erow * 3 + l15]);
            }
        }
    }
}

// ---------------------------------------------------------------------------
// Node kernel: h_new = silu([h|h_neigh]@NW1+nb1)@NW2+nb2 -> gelu -> LayerNorm
// ---------------------------------------------------------------------------
__global__ __launch_bounds__(256, 2) void node_kernel(
    unsigned short* hbf,                 // in/out (each row touched by 1 block)
    const float* __restrict__ h_neigh,
    const float* __restrict__ nw1,       // [128,64]
    const float* __restrict__ nb1,
    const float* __restrict__ nw2,       // [64,64]
    const float* __restrict__ nb2,
    const float* __restrict__ ln_g,
    const float* __restrict__ ln_b)
{
    __shared__ __align__(16) unsigned short w1T[64 * 128];
    __shared__ __align__(16) unsigned short w2T[64 * 64];
    __shared__ __align__(16) unsigned short fA[64 * 128];
    __shared__ float nb1s[64], nb2s[64], gs[64], bs[64];

    const int tid  = threadIdx.x;
    const int wave = tid >> 6;
    const int lane = tid & 63;
    const int quad = lane >> 4;
    const int l15  = lane & 15;

    for (int i = tid; i < 64 * 128; i += 256) {
        int n = i >> 7, k = i & 127;
        w1T[i] = f2bf(nw1[k * 64 + n]);
    }
    for (int i = tid; i < 64 * 64; i += 256) {
        int n = i >> 6, k = i & 63;
        w2T[i] = f2bf(nw2[k * 64 + n]);
    }
    if (tid < 64) {
        nb1s[tid] = nb1[tid]; nb2s[tid] = nb2[tid];
        gs[tid] = ln_g[tid]; bs[tid] = ln_b[tid];
    }
    __syncthreads();

    bf16x8 b1[4][4], b2[2][4];
#pragma unroll
    for (int nt = 0; nt < 4; ++nt) {
#pragma unroll
        for (int ks = 0; ks < 4; ++ks)
            b1[ks][nt] = *(const bf16x8*)&w1T[(nt * 16 + l15) * 128 + ks * 32 + quad * 8];
#pragma unroll
        for (int ks = 0; ks < 2; ++ks)
            b2[ks][nt] = *(const bf16x8*)&w2T[(nt * 16 + l15) * 64 + ks * 32 + quad * 8];
    }

    const int NT = (NN + 63) / 64;
    for (int t = blockIdx.x; t < NT; t += gridDim.x) {
        __syncthreads();
        const int n0 = t * 64;
        {
            int e = tid >> 2, part = tid & 3;
            int n = n0 + e; if (n >= NN) n = NN - 1;
            if (part < 2) {
                const uint4* s = (const uint4*)(hbf + n * 64 + (part & 1) * 32);
                uint4* d = (uint4*)(fA + e * 128 + part * 32);
                d[0] = s[0]; d[1] = s[1]; d[2] = s[2]; d[3] = s[3];
            } else {
                const float4* s = (const float4*)(h_neigh + n * 64 + (part & 1) * 32);
                unsigned short* d = fA + e * 128 + 64 + (part & 1) * 32;
#pragma unroll
                for (int j = 0; j < 8; ++j) {
                    float4 v = s[j];
                    d[j * 4 + 0] = f2bf(v.x); d[j * 4 + 1] = f2bf(v.y);
                    d[j * 4 + 2] = f2bf(v.z); d[j * 4 + 3] = f2bf(v.w);
                }
            }
        }
        __syncthreads();

        f32x4 acc[4];
#pragma unroll
        for (int nt = 0; nt < 4; ++nt) acc[nt] = (f32x4){0.f, 0.f, 0.f, 0.f};
        const unsigned short* aBase = &fA[(wave * 16 + l15) * 128 + quad * 8];
#pragma unroll
        for (int ks = 0; ks < 4; ++ks) {
            bf16x8 a = *(const bf16x8*)(aBase + ks * 32);
#pragma unroll
            for (int nt = 0; nt < 4; ++nt)
                acc[nt] = __builtin_amdgcn_mfma_f32_16x16x32_bf16(a, b1[ks][nt], acc[nt], 0, 0, 0);
        }
        __syncthreads();

        unsigned short* tA = fA;
#pragma unroll
        for (int nt = 0; nt < 4; ++nt) {
            int col = nt * 16 + l15;
#pragma unroll
            for (int r = 0; r < 4; ++r) {
                int erow = wave * 16 + quad * 4 + r;
                float v = acc[nt][r] + nb1s[col];
                tA[erow * 64 + col] = f2bf(silu_f(v));
            }
        }
        f32x4 acc2[4];
#pragma unroll
        for (int nt = 0; nt < 4; ++nt) acc2[nt] = (f32x4){0.f, 0.f, 0.f, 0.f};
        const unsigned short* aB2 = &tA[(wave * 16 + l15) * 64 + quad * 8];
#pragma unroll
        for (int ks = 0; ks < 2; ++ks) {
            bf16x8 a = *(const bf16x8*)(aB2 + ks * 32);
#pragma unroll
            for (int nt = 0; nt < 4; ++nt)
                acc2[nt] = __builtin_amdgcn_mfma_f32_16x16x32_bf16(a, b2[ks][nt], acc2[nt], 0, 0, 0);
        }
        // gelu (exact) + LayerNorm, 16-lane reductions per row
        float vals[4][4];
        float sum[4] = {0.f, 0.f, 0.f, 0.f}, ss[4] = {0.f, 0.f, 0.f, 0.f};
#pragma unroll
        for (int nt = 0; nt < 4; ++nt) {
            int col = nt * 16 + l15;
#pragma unroll
            for (int r = 0; r < 4; ++r) {
                float v = acc2[nt][r] + nb2s[col];
                float g = 0.5f * v * (1.0f + erff(v * 0.70710678118654752f));
                vals[nt][r] = g;
                sum[r] += g;
                ss[r] += g * g;
            }
        }
#pragma unroll
        for (int r = 0; r < 4; ++r) {
            float s1 = sum[r], s2 = ss[r];
            s1 += __shfl_xor(s1, 1); s2 += __shfl_xor(s2, 1);
            s1 += __shfl_xor(s1, 2); s2 += __shfl_xor(s2, 2);
            s1 += __shfl_xor(s1, 4); s2 += __shfl_xor(s2, 4);
            s1 += __shfl_xor(s1, 8); s2 += __shfl_xor(s2, 8);
            sum[r] = s1; ss[r] = s2;
        }
#pragma unroll
        for (int r = 0; r < 4; ++r) {
            float mean = sum[r] * (1.0f / 64.0f);
            float var  = ss[r] * (1.0f / 64.0f) - mean * mean;
            float rstd = rsqrtf(var + 1e-5f);
            int n = n0 + wave * 16 + quad * 4 + r;
            if (n < NN) {
#pragma unroll
                for (int nt = 0; nt < 4; ++nt) {
                    int col = nt * 16 + l15;
                    float y = (vals[nt][r] - mean) * rstd * gs[col] + bs[col];
                    hbf[n * 64 + col] = f2bf(y);
                }
            }
        }
    }
}

__global__ void init_h(const float* __restrict__ nf, unsigned short* __restrict__ hbf) {
    int i = blockIdx.x * 256 + threadIdx.x;
    if (i < NN * 64) hbf[i] = f2bf(nf[i]);
}
__global__ void init_x(const float* __restrict__ xyz, float* __restrict__ xcur) {
    int i = blockIdx.x * 256 + threadIdx.x;
    if (i < NN * 3) xcur[i] = xyz[i];
}
__global__ void deg_kernel(const int* __restrict__ dst, float* __restrict__ deg) {
    int i = blockIdx.x * 256 + threadIdx.x;
    if (i < NE) atomicAdd(&deg[dst[i]], 1.0f);
}
__global__ void xupd(const float* __restrict__ x_sum, const float* __restrict__ deg,
                     float* __restrict__ xcur) {
    int n = blockIdx.x * 256 + threadIdx.x;
    if (n < NN) {
        float id = 1.0f / fmaxf(deg[n], 1.0f);
        xcur[n * 3 + 0] += x_sum[n * 3 + 0] * id;
        xcur[n * 3 + 1] += x_sum[n * 3 + 1] * id;
        xcur[n * 3 + 2] += x_sum[n * 3 + 2] * id;
    }
}
__global__ __launch_bounds__(256) void head_kernel(
    const unsigned short* __restrict__ hbf,
    const float* __restrict__ out_w,   // [64,32]
    const float* __restrict__ out_b,   // [32]
    float* __restrict__ out)
{
    __shared__ float w[64 * 32];
    __shared__ float b[32];
    int tid = threadIdx.x;
    for (int i = tid; i < 64 * 32; i += 256) w[i] = out_w[i];
    if (tid < 32) b[tid] = out_b[tid];
    __syncthreads();
    int co = tid & 31, nl = tid >> 5;
    for (int n = blockIdx.x * 8 + nl; n < NN; n += gridDim.x * 8) {
        float acc = b[co];
#pragma unroll 8
        for (int k = 0; k < 64; ++k)
            acc += bf2f(hbf[n * 64 + k]) * w[k * 32 + co];
        out[n * 32 + co] = acc;
    }
}

extern "C" void kernel_launch(void* const* d_in, const int* in_sizes, int n_in,
                              void* d_out, int out_size, void* d_ws, size_t ws_size,
                              hipStream_t stream)
{
    const float* node_feat = (const float*)d_in[0];
    const float* xyz   = (const float*)d_in[1];
    const int*   src   = (const int*)d_in[2];
    const int*   dst   = (const int*)d_in[3];
    const float* ew1   = (const float*)d_in[4];
    const float* eb1   = (const float*)d_in[5];
    const float* ew2   = (const float*)d_in[6];
    const float* eb2   = (const float*)d_in[7];
    const float* cw1   = (const float*)d_in[8];
    const float* cb1   = (const float*)d_in[9];
    const float* cw2   = (const float*)d_in[10];
    const float* nw1   = (const float*)d_in[11];
    const float* nb1   = (const float*)d_in[12];
    const float* nw2   = (const float*)d_in[13];
    const float* nb2   = (const float*)d_in[14];
    const float* ln_g  = (const float*)d_in[15];
    const float* ln_b  = (const float*)d_in[16];
    const float* out_w = (const float*)d_in[17];
    const float* out_b = (const float*)d_in[18];
    float* out = (float*)d_out;

    char* ws = (char*)d_ws;
    float* h_neigh = (float*)ws;               ws += (size_t)NN * 64 * 4;
    float* x_cur   = (float*)ws;               ws += (size_t)NN * 3 * 4;
    float* x_sum   = (float*)ws;               ws += (size_t)NN * 3 * 4;
    float* deg     = (float*)ws;               ws += (size_t)NN * 4;
    unsigned short* hbf = (unsigned short*)ws; ws += (size_t)NN * 64 * 2;

    hipMemsetAsync(deg, 0, (size_t)NN * 4, stream);
    init_h<<<(NN * 64 + 255) / 256, 256, 0, stream>>>(node_feat, hbf);
    init_x<<<(NN * 3 + 255) / 256, 256, 0, stream>>>(xyz, x_cur);
    deg_kernel<<<(NE + 255) / 256, 256, 0, stream>>>(dst, deg);

    for (int l = 0; l < 2; ++l) {
        hipMemsetAsync(h_neigh, 0, (size_t)NN * 64 * 4, stream);
        hipMemsetAsync(x_sum, 0, (size_t)NN * 3 * 4, stream);
        edge_kernel<<<2048, 256, 0, stream>>>(
            x_cur, hbf, src, dst,
            ew1 + l * 129 * 64, eb1 + l * 64,
            ew2 + l * 64 * 64, eb2 + l * 64,
            cw1 + l * 64 * 64, cb1 + l * 64, cw2 + l * 64,
            h_neigh, x_sum);
        if (l == 0)
            xupd<<<(NN + 255) / 256, 256, 0, stream>>>(x_sum, deg, x_cur);
        node_kernel<<<1024, 256, 0, stream>>>(
            hbf, h_neigh,
            nw1 + l * 128 * 64, nb1 + l * 64,
            nw2 + l * 64 * 64, nb2 + l * 64,
            ln_g, ln_b);
    }
    head_kernel<<<1024, 256, 0, stream>>>(hbf, out_w, out_b, out);
}

// Round 2
// 1255.617 us; speedup vs baseline: 1.1186x; 1.1186x over previous
//
#include <hip/hip_runtime.h>
#include <hip/hip_bf16.h>

#define NN 100000
#define NE 1600000
#define SW 136   // padded stride (shorts) for [64][128] bf16 tiles (2-way-free banks)
#define ST 68    // padded stride (shorts) for [64][64] bf16 tiles

typedef __attribute__((ext_vector_type(8))) short bf16x8;
typedef __attribute__((ext_vector_type(4))) float f32x4;

__device__ __forceinline__ unsigned short f2bf(float f) {
    union { float f; unsigned int u; } v; v.f = f;
    unsigned int u = v.u + 0x7fff + ((v.u >> 16) & 1);
    return (unsigned short)(u >> 16);
}
__device__ __forceinline__ float bf2f(unsigned short h) {
    union { unsigned int u; float f; } v; v.u = ((unsigned int)h) << 16;
    return v.f;
}
__device__ __forceinline__ float silu_f(float v) {
    return v / (1.0f + __expf(-v));
}

// ---------------------------------------------------------------------------
// Edge kernel: per 64-edge tile, fused 3-GEMM MLP chain + atomic scatter.
// b1 fragments read from LDS (w1T, padded stride); b2/b3 in registers.
// A-layout: A[m=lane&15][k=quad*8+j]; C/D: col=lane&15, row=quad*4+reg
// ---------------------------------------------------------------------------
__global__ __launch_bounds__(256, 4) void edge_kernel(
    const float* __restrict__ xcur,
    const unsigned short* __restrict__ hbf,
    const int* __restrict__ src,
    const int* __restrict__ dst,
    const float* __restrict__ ew1,   // [129,64]
    const float* __restrict__ eb1,
    const float* __restrict__ ew2,   // [64,64]
    const float* __restrict__ eb2,
    const float* __restrict__ cw1,   // [64,64]
    const float* __restrict__ cb1,
    const float* __restrict__ cw2,   // [64]
    float* __restrict__ h_neigh,     // [N,64]
    float* __restrict__ x_sum)       // [N,3]
{
    __shared__ __align__(16) unsigned short w1T[64 * SW]; // resident B^T, padded
    __shared__ __align__(16) unsigned short fA[64 * SW];  // A-tile; pre-loop: w2/c1 stage; in-loop: fA then tA|tB
    __shared__ float eb1s[64], eb2s[64], cb1s[64], cw2s[64], w1l[64];
    __shared__ float xds[64 * 3], rads[64];
    __shared__ int dstL[64];

    const int tid  = threadIdx.x;
    const int wave = tid >> 6;
    const int lane = tid & 63;
    const int quad = lane >> 4;
    const int l15  = lane & 15;

    // stage w1 (transposed, padded) resident; w2/c1 transiently into fA
    for (int i = tid; i < 64 * 128; i += 256) {
        int n = i >> 7, k = i & 127;
        w1T[n * SW + k] = f2bf(ew1[k * 64 + n]);
    }
    for (int i = tid; i < 64 * 64; i += 256) {
        int n = i >> 6, k = i & 63;
        fA[n * 64 + k]        = f2bf(ew2[k * 64 + n]);
        fA[4096 + n * 64 + k] = f2bf(cw1[k * 64 + n]);
    }
    if (tid < 64) {
        eb1s[tid] = eb1[tid]; eb2s[tid] = eb2[tid]; cb1s[tid] = cb1[tid];
        cw2s[tid] = cw2[tid]; w1l[tid] = ew1[128 * 64 + tid];
    }
    __syncthreads();

    // preload b2/b3 fragments into registers (reused across all tiles)
    bf16x8 b2[2][4], b3[2][4];
#pragma unroll
    for (int nt = 0; nt < 4; ++nt)
#pragma unroll
        for (int ks = 0; ks < 2; ++ks) {
            b2[ks][nt] = *(const bf16x8*)&fA[(nt * 16 + l15) * 64 + ks * 32 + quad * 8];
            b3[ks][nt] = *(const bf16x8*)&fA[4096 + (nt * 16 + l15) * 64 + ks * 32 + quad * 8];
        }

    for (int t = blockIdx.x; t < NE / 64; t += gridDim.x) {
        __syncthreads();  // protect restaging vs previous iteration's reads
        const int e0 = t * 64;
        {   // gather h[src] | h[dst] into fA (4 threads per edge, 32 bf16 each)
            int e = tid >> 2, part = tid & 3;
            int eg = e0 + e;
            int node = (part < 2) ? src[eg] : dst[eg];
            const uint4* s = (const uint4*)(hbf + node * 64 + (part & 1) * 32);
            uint4* d = (uint4*)(fA + e * SW + part * 32);
            d[0] = s[0]; d[1] = s[1]; d[2] = s[2]; d[3] = s[3];
        }
        if (tid < 64) {  // radial + normalized x_diff (fp32)
            int eg = e0 + tid;
            int sn = src[eg], dn = dst[eg];
            float dx = xcur[sn * 3 + 0] - xcur[dn * 3 + 0];
            float dy = xcur[sn * 3 + 1] - xcur[dn * 3 + 1];
            float dz = xcur[sn * 3 + 2] - xcur[dn * 3 + 2];
            float rad = dx * dx + dy * dy + dz * dz;
            float inv = 1.0f / (sqrtf(rad) + 1e-30f);
            xds[tid * 3 + 0] = dx * inv;
            xds[tid * 3 + 1] = dy * inv;
            xds[tid * 3 + 2] = dz * inv;
            rads[tid] = rad;
            dstL[tid] = dn;
        }
        __syncthreads();

        // ---- GEMM1: f[:,0:128] @ W1[0:128,:], K=128 (b1 frags from LDS)
        f32x4 acc[4];
#pragma unroll
        for (int nt = 0; nt < 4; ++nt) acc[nt] = (f32x4){0.f, 0.f, 0.f, 0.f};
        const unsigned short* aBase = &fA[(wave * 16 + l15) * SW + quad * 8];
        const unsigned short* bBase = &w1T[l15 * SW + quad * 8];
#pragma unroll
        for (int ks = 0; ks < 4; ++ks) {
            bf16x8 a = *(const bf16x8*)(aBase + ks * 32);
#pragma unroll
            for (int nt = 0; nt < 4; ++nt) {
                bf16x8 b = *(const bf16x8*)(bBase + nt * 16 * SW + ks * 32);
                acc[nt] = __builtin_amdgcn_mfma_f32_16x16x32_bf16(a, b, acc[nt], 0, 0, 0);
            }
        }
        __syncthreads();  // fA (as A-input) dead; tA/tB alias it

        unsigned short* tA = fA;            // [64][ST]
        unsigned short* tB = fA + 64 * ST;  // [64][ST]
        // epilogue: + bias + radial rank-1 (fp32) + silu -> tA (bf16)
#pragma unroll
        for (int nt = 0; nt < 4; ++nt) {
            int col = nt * 16 + l15;
#pragma unroll
            for (int r = 0; r < 4; ++r) {
                int erow = wave * 16 + quad * 4 + r;
                float v = acc[nt][r] + eb1s[col] + rads[erow] * w1l[col];
                tA[erow * ST + col] = f2bf(silu_f(v));
            }
        }
        // ---- GEMM2: t1 @ W2, K=64 (wave-local rows, no barrier needed)
        f32x4 acc2[4];
#pragma unroll
        for (int nt = 0; nt < 4; ++nt) acc2[nt] = (f32x4){0.f, 0.f, 0.f, 0.f};
        const unsigned short* aB2 = &tA[(wave * 16 + l15) * ST + quad * 8];
#pragma unroll
        for (int ks = 0; ks < 2; ++ks) {
            bf16x8 a = *(const bf16x8*)(aB2 + ks * 32);
#pragma unroll
            for (int nt = 0; nt < 4; ++nt)
                acc2[nt] = __builtin_amdgcn_mfma_f32_16x16x32_bf16(a, b2[ks][nt], acc2[nt], 0, 0, 0);
        }
        // epilogue: silu -> msg_h; atomic scatter + tB (bf16)
#pragma unroll
        for (int nt = 0; nt < 4; ++nt) {
            int col = nt * 16 + l15;
#pragma unroll
            for (int r = 0; r < 4; ++r) {
                int erow = wave * 16 + quad * 4 + r;
                float v = silu_f(acc2[nt][r] + eb2s[col]);
                atomicAdd(&h_neigh[dstL[erow] * 64 + col], v);
                tB[erow * ST + col] = f2bf(v);
            }
        }
        // ---- GEMM3: msg_h @ CW1, K=64
        f32x4 acc3[4];
#pragma unroll
        for (int nt = 0; nt < 4; ++nt) acc3[nt] = (f32x4){0.f, 0.f, 0.f, 0.f};
        const unsigned short* aB3 = &tB[(wave * 16 + l15) * ST + quad * 8];
#pragma unroll
        for (int ks = 0; ks < 2; ++ks) {
            bf16x8 a = *(const bf16x8*)(aB3 + ks * 32);
#pragma unroll
            for (int nt = 0; nt < 4; ++nt)
                acc3[nt] = __builtin_amdgcn_mfma_f32_16x16x32_bf16(a, b3[ks][nt], acc3[nt], 0, 0, 0);
        }
        // coord head: silu, dot with cw2 (fp32), 16-lane reduce, scatter msg_x
        float part_[4] = {0.f, 0.f, 0.f, 0.f};
#pragma unroll
        for (int nt = 0; nt < 4; ++nt) {
            int col = nt * 16 + l15;
#pragma unroll
            for (int r = 0; r < 4; ++r) {
                float v = silu_f(acc3[nt][r] + cb1s[col]);
                part_[r] += v * cw2s[col];
            }
        }
#pragma unroll
        for (int r = 0; r < 4; ++r) {
            float p = part_[r];
            p += __shfl_xor(p, 1);
            p += __shfl_xor(p, 2);
            p += __shfl_xor(p, 4);
            p += __shfl_xor(p, 8);
            part_[r] = p;
        }
        if (l15 < 3) {
#pragma unroll
            for (int r = 0; r < 4; ++r) {
                int erow = wave * 16 + quad * 4 + r;
                atomicAdd(&x_sum[dstL[erow] * 3 + l15], part_[r] * xds[erow * 3 + l15]);
            }
        }
    }
}

// ---------------------------------------------------------------------------
// Node kernel: h_new = silu([h|h_neigh]@NW1+nb1)@NW2+nb2 -> gelu -> LayerNorm
// ---------------------------------------------------------------------------
__global__ __launch_bounds__(256, 4) void node_kernel(
    unsigned short* hbf,                 // in/out (each row touched by 1 block)
    const float* __restrict__ h_neigh,
    const float* __restrict__ nw1,       // [128,64]
    const float* __restrict__ nb1,
    const float* __restrict__ nw2,       // [64,64]
    const float* __restrict__ nb2,
    const float* __restrict__ ln_g,
    const float* __restrict__ ln_b)
{
    __shared__ __align__(16) unsigned short w1T[64 * SW];
    __shared__ __align__(16) unsigned short fA[64 * SW];
    __shared__ float nb1s[64], nb2s[64], gs[64], bs[64];

    const int tid  = threadIdx.x;
    const int wave = tid >> 6;
    const int lane = tid & 63;
    const int quad = lane >> 4;
    const int l15  = lane & 15;

    for (int i = tid; i < 64 * 128; i += 256) {
        int n = i >> 7, k = i & 127;
        w1T[n * SW + k] = f2bf(nw1[k * 64 + n]);
    }
    for (int i = tid; i < 64 * 64; i += 256) {
        int n = i >> 6, k = i & 63;
        fA[n * 64 + k] = f2bf(nw2[k * 64 + n]);
    }
    if (tid < 64) {
        nb1s[tid] = nb1[tid]; nb2s[tid] = nb2[tid];
        gs[tid] = ln_g[tid]; bs[tid] = ln_b[tid];
    }
    __syncthreads();

    bf16x8 b2[2][4];
#pragma unroll
    for (int nt = 0; nt < 4; ++nt)
#pragma unroll
        for (int ks = 0; ks < 2; ++ks)
            b2[ks][nt] = *(const bf16x8*)&fA[(nt * 16 + l15) * 64 + ks * 32 + quad * 8];

    const int NT = (NN + 63) / 64;
    for (int t = blockIdx.x; t < NT; t += gridDim.x) {
        __syncthreads();
        const int n0 = t * 64;
        {
            int e = tid >> 2, part = tid & 3;
            int n = n0 + e; if (n >= NN) n = NN - 1;
            if (part < 2) {
                const uint4* s = (const uint4*)(hbf + n * 64 + (part & 1) * 32);
                uint4* d = (uint4*)(fA + e * SW + part * 32);
                d[0] = s[0]; d[1] = s[1]; d[2] = s[2]; d[3] = s[3];
            } else {
                const float4* s = (const float4*)(h_neigh + n * 64 + (part & 1) * 32);
                unsigned short* d = fA + e * SW + 64 + (part & 1) * 32;
#pragma unroll
                for (int j = 0; j < 8; ++j) {
                    float4 v = s[j];
                    d[j * 4 + 0] = f2bf(v.x); d[j * 4 + 1] = f2bf(v.y);
                    d[j * 4 + 2] = f2bf(v.z); d[j * 4 + 3] = f2bf(v.w);
                }
            }
        }
        __syncthreads();

        f32x4 acc[4];
#pragma unroll
        for (int nt = 0; nt < 4; ++nt) acc[nt] = (f32x4){0.f, 0.f, 0.f, 0.f};
        const unsigned short* aBase = &fA[(wave * 16 + l15) * SW + quad * 8];
        const unsigned short* bBase = &w1T[l15 * SW + quad * 8];
#pragma unroll
        for (int ks = 0; ks < 4; ++ks) {
            bf16x8 a = *(const bf16x8*)(aBase + ks * 32);
#pragma unroll
            for (int nt = 0; nt < 4; ++nt) {
                bf16x8 b = *(const bf16x8*)(bBase + nt * 16 * SW + ks * 32);
                acc[nt] = __builtin_amdgcn_mfma_f32_16x16x32_bf16(a, b, acc[nt], 0, 0, 0);
            }
        }
        __syncthreads();

        unsigned short* tA = fA;
#pragma unroll
        for (int nt = 0; nt < 4; ++nt) {
            int col = nt * 16 + l15;
#pragma unroll
            for (int r = 0; r < 4; ++r) {
                int erow = wave * 16 + quad * 4 + r;
                float v = acc[nt][r] + nb1s[col];
                tA[erow * ST + col] = f2bf(silu_f(v));
            }
        }
        f32x4 acc2[4];
#pragma unroll
        for (int nt = 0; nt < 4; ++nt) acc2[nt] = (f32x4){0.f, 0.f, 0.f, 0.f};
        const unsigned short* aB2 = &tA[(wave * 16 + l15) * ST + quad * 8];
#pragma unroll
        for (int ks = 0; ks < 2; ++ks) {
            bf16x8 a = *(const bf16x8*)(aB2 + ks * 32);
#pragma unroll
            for (int nt = 0; nt < 4; ++nt)
                acc2[nt] = __builtin_amdgcn_mfma_f32_16x16x32_bf16(a, b2[ks][nt], acc2[nt], 0, 0, 0);
        }
        // gelu (exact) + LayerNorm, 16-lane reductions per row
        float vals[4][4];
        float sum[4] = {0.f, 0.f, 0.f, 0.f}, ss[4] = {0.f, 0.f, 0.f, 0.f};
#pragma unroll
        for (int nt = 0; nt < 4; ++nt) {
            int col = nt * 16 + l15;
#pragma unroll
            for (int r = 0; r < 4; ++r) {
                float v = acc2[nt][r] + nb2s[col];
                float g = 0.5f * v * (1.0f + erff(v * 0.70710678118654752f));
                vals[nt][r] = g;
                sum[r] += g;
                ss[r] += g * g;
            }
        }
#pragma unroll
        for (int r = 0; r < 4; ++r) {
            float s1 = sum[r], s2 = ss[r];
            s1 += __shfl_xor(s1, 1); s2 += __shfl_xor(s2, 1);
            s1 += __shfl_xor(s1, 2); s2 += __shfl_xor(s2, 2);
            s1 += __shfl_xor(s1, 4); s2 += __shfl_xor(s2, 4);
            s1 += __shfl_xor(s1, 8); s2 += __shfl_xor(s2, 8);
            sum[r] = s1; ss[r] = s2;
        }
#pragma unroll
        for (int r = 0; r < 4; ++r) {
            float mean = sum[r] * (1.0f / 64.0f);
            float var  = ss[r] * (1.0f / 64.0f) - mean * mean;
            float rstd = rsqrtf(var + 1e-5f);
            int n = n0 + wave * 16 + quad * 4 + r;
            if (n < NN) {
#pragma unroll
                for (int nt = 0; nt < 4; ++nt) {
                    int col = nt * 16 + l15;
                    float y = (vals[nt][r] - mean) * rstd * gs[col] + bs[col];
                    hbf[n * 64 + col] = f2bf(y);
                }
            }
        }
    }
}

__global__ void init_h(const float* __restrict__ nf, unsigned short* __restrict__ hbf) {
    int i = blockIdx.x * 256 + threadIdx.x;
    if (i < NN * 64) hbf[i] = f2bf(nf[i]);
}
__global__ void init_x(const float* __restrict__ xyz, float* __restrict__ xcur) {
    int i = blockIdx.x * 256 + threadIdx.x;
    if (i < NN * 3) xcur[i] = xyz[i];
}
__global__ void deg_kernel(const int* __restrict__ dst, float* __restrict__ deg) {
    int i = blockIdx.x * 256 + threadIdx.x;
    if (i < NE) atomicAdd(&deg[dst[i]], 1.0f);
}
__global__ void xupd(const float* __restrict__ x_sum, const float* __restrict__ deg,
                     float* __restrict__ xcur) {
    int n = blockIdx.x * 256 + threadIdx.x;
    if (n < NN) {
        float id = 1.0f / fmaxf(deg[n], 1.0f);
        xcur[n * 3 + 0] += x_sum[n * 3 + 0] * id;
        xcur[n * 3 + 1] += x_sum[n * 3 + 1] * id;
        xcur[n * 3 + 2] += x_sum[n * 3 + 2] * id;
    }
}
__global__ __launch_bounds__(256) void head_kernel(
    const unsigned short* __restrict__ hbf,
    const float* __restrict__ out_w,   // [64,32]
    const float* __restrict__ out_b,   // [32]
    float* __restrict__ out)
{
    __shared__ float w[64 * 32];
    __shared__ float b[32];
    int tid = threadIdx.x;
    for (int i = tid; i < 64 * 32; i += 256) w[i] = out_w[i];
    if (tid < 32) b[tid] = out_b[tid];
    __syncthreads();
    int co = tid & 31, nl = tid >> 5;
    for (int n = blockIdx.x * 8 + nl; n < NN; n += gridDim.x * 8) {
        float acc = b[co];
#pragma unroll 8
        for (int k = 0; k < 64; ++k)
            acc += bf2f(hbf[n * 64 + k]) * w[k * 32 + co];
        out[n * 32 + co] = acc;
    }
}

extern "C" void kernel_launch(void* const* d_in, const int* in_sizes, int n_in,
                              void* d_out, int out_size, void* d_ws, size_t ws_size,
                              hipStream_t stream)
{
    const float* node_feat = (const float*)d_in[0];
    const float* xyz   = (const float*)d_in[1];
    const int*   src   = (const int*)d_in[2];
    const int*   dst   = (const int*)d_in[3];
    const float* ew1   = (const float*)d_in[4];
    const float* eb1   = (const float*)d_in[5];
    const float* ew2   = (const float*)d_in[6];
    const float* eb2   = (const float*)d_in[7];
    const float* cw1   = (const float*)d_in[8];
    const float* cb1   = (const float*)d_in[9];
    const float* cw2   = (const float*)d_in[10];
    const float* nw1   = (const float*)d_in[11];
    const float* nb1   = (const float*)d_in[12];
    const float* nw2   = (const float*)d_in[13];
    const float* nb2   = (const float*)d_in[14];
    const float* ln_g  = (const float*)d_in[15];
    const float* ln_b  = (const float*)d_in[16];
    const float* out_w = (const float*)d_in[17];
    const float* out_b = (const float*)d_in[18];
    float* out = (float*)d_out;

    char* ws = (char*)d_ws;
    float* h_neigh = (float*)ws;               ws += (size_t)NN * 64 * 4;
    float* x_cur   = (float*)ws;               ws += (size_t)NN * 3 * 4;
    float* x_sum   = (float*)ws;               ws += (size_t)NN * 3 * 4;
    float* deg     = (float*)ws;               ws += (size_t)NN * 4;
    unsigned short* hbf = (unsigned short*)ws; ws += (size_t)NN * 64 * 2;

    hipMemsetAsync(deg, 0, (size_t)NN * 4, stream);
    init_h<<<(NN * 64 + 255) / 256, 256, 0, stream>>>(node_feat, hbf);
    init_x<<<(NN * 3 + 255) / 256, 256, 0, stream>>>(xyz, x_cur);
    deg_kernel<<<(NE + 255) / 256, 256, 0, stream>>>(dst, deg);

    for (int l = 0; l < 2; ++l) {
        hipMemsetAsync(h_neigh, 0, (size_t)NN * 64 * 4, stream);
        hipMemsetAsync(x_sum, 0, (size_t)NN * 3 * 4, stream);
        edge_kernel<<<4096, 256, 0, stream>>>(
            x_cur, hbf, src, dst,
            ew1 + l * 129 * 64, eb1 + l * 64,
            ew2 + l * 64 * 64, eb2 + l * 64,
            cw1 + l * 64 * 64, cb1 + l * 64, cw2 + l * 64,
            h_neigh, x_sum);
        if (l == 0)
            xupd<<<(NN + 255) / 256, 256, 0, stream>>>(x_sum, deg, x_cur);
        node_kernel<<<1024, 256, 0, stream>>>(
            hbf, h_neigh,
            nw1 + l * 128 * 64, nb1 + l * 64,
            nw2 + l * 64 * 64, nb2 + l * 64,
            ln_g, ln_b);
    }
    head_kernel<<<1024, 256, 0, stream>>>(hbf, out_w, out_b, out);
}

// Round 3
// 1199.162 us; speedup vs baseline: 1.1713x; 1.0471x over previous
//
#include <hip/hip_runtime.h>
#include <hip/hip_bf16.h>

#define NN 100000
#define NE 1600000
#define SW 136   // padded stride (shorts) for [64][128] bf16 weight tiles
#define ST 68    // padded stride (shorts) for [64][64] / [16][64] bf16 tiles

typedef __attribute__((ext_vector_type(8))) short bf16x8;
typedef __attribute__((ext_vector_type(4))) float f32x4;

__device__ __forceinline__ unsigned short f2bf(float f) {
    union { float f; unsigned int u; } v; v.f = f;
    unsigned int u = v.u + 0x7fff + ((v.u >> 16) & 1);
    return (unsigned short)(u >> 16);
}
__device__ __forceinline__ float bf2f(unsigned short h) {
    union { unsigned int u; float f; } v; v.u = ((unsigned int)h) << 16;
    return v.f;
}
__device__ __forceinline__ float silu_f(float v) {
    return v / (1.0f + __expf(-v));
}

// ---------------------------------------------------------------------------
// Edge kernel, barrier-free main loop: each WAVE owns independent 16-edge
// tiles. A-frags gathered straight from global into registers; edge metadata
// via shuffles; inter-GEMM transposes via per-wave LDS slice (same-wave LDS
// is program-ordered -> no barriers). Atomics are fire-and-forget.
// MFMA 16x16x32 bf16. A[m=lane&15][k=quad*8+j]; C/D: col=lane&15,row=quad*4+r
// ---------------------------------------------------------------------------
__global__ __launch_bounds__(256, 4) void edge_kernel(
    const float* __restrict__ xcur,
    const unsigned short* __restrict__ hbf,
    const int* __restrict__ src,
    const int* __restrict__ dst,
    const float* __restrict__ ew1,   // [129,64]
    const float* __restrict__ eb1,
    const float* __restrict__ ew2,   // [64,64]
    const float* __restrict__ eb2,
    const float* __restrict__ cw1,   // [64,64]
    const float* __restrict__ cb1,
    const float* __restrict__ cw2,   // [64]
    float* __restrict__ h_neigh,     // [N,64]
    float* __restrict__ x_sum)       // [N,3]
{
    __shared__ __align__(16) unsigned short w1T[64 * SW];      // B^T GEMM1
    __shared__ __align__(16) unsigned short c1T[64 * ST];      // B^T GEMM3
    __shared__ __align__(16) unsigned short tAll[4 * 16 * ST]; // per-wave link buf
    __shared__ float eb1s[64], eb2s[64], cb1s[64], cw2s[64], w1l[64];

    const int tid  = threadIdx.x;
    const int wave = tid >> 6;
    const int lane = tid & 63;
    const int quad = lane >> 4;
    const int l15  = lane & 15;

    // stage weights (coalesced global reads: n fastest)
    for (int i = tid; i < 64 * 128; i += 256) {
        int n = i & 63, k = i >> 6;
        w1T[n * SW + k] = f2bf(ew1[k * 64 + n]);
    }
    for (int i = tid; i < 64 * 64; i += 256) {
        int n = i & 63, k = i >> 6;
        c1T[n * ST + k] = f2bf(cw1[k * 64 + n]);
    }
    if (tid < 64) {
        eb1s[tid] = eb1[tid]; eb2s[tid] = eb2[tid]; cb1s[tid] = cb1[tid];
        cw2s[tid] = cw2[tid]; w1l[tid] = ew1[128 * 64 + tid];
    }
    // b2 fragments straight from global (L2-hit), once per block
    bf16x8 b2[2][4];
#pragma unroll
    for (int ks = 0; ks < 2; ++ks)
#pragma unroll
        for (int nt = 0; nt < 4; ++nt) {
#pragma unroll
            for (int j = 0; j < 8; ++j) {
                int k = ks * 32 + quad * 8 + j;
                ((unsigned short*)&b2[ks][nt])[j] = f2bf(ew2[k * 64 + nt * 16 + l15]);
            }
        }
    __syncthreads();   // the only barrier

    unsigned short* tW = tAll + wave * 16 * ST;

    for (int t = blockIdx.x * 4 + wave; t < NE / 16; t += gridDim.x * 4) {
        const int e0 = t * 16;
        // lanes 0..15 load edge metadata
        int sn = 0, dn_ = 0; float rad = 0.f, xdx = 0.f, xdy = 0.f, xdz = 0.f;
        if (lane < 16) {
            int eg = e0 + lane;
            sn = src[eg]; dn_ = dst[eg];
            float dx = xcur[sn * 3 + 0] - xcur[dn_ * 3 + 0];
            float dy = xcur[sn * 3 + 1] - xcur[dn_ * 3 + 1];
            float dz = xcur[sn * 3 + 2] - xcur[dn_ * 3 + 2];
            rad = dx * dx + dy * dy + dz * dz;
            float inv = 1.0f / (sqrtf(rad) + 1e-30f);
            xdx = dx * inv; xdy = dy * inv; xdz = dz * inv;
        }
        const int rowS = __shfl(sn, l15);
        const int rowD = __shfl(dn_, l15);
        // A-fragments direct from global
        const unsigned short* ps = hbf + (size_t)rowS * 64 + quad * 8;
        const unsigned short* pd = hbf + (size_t)rowD * 64 + quad * 8;
        bf16x8 a0 = *(const bf16x8*)(ps);
        bf16x8 a1 = *(const bf16x8*)(ps + 32);
        bf16x8 a2 = *(const bf16x8*)(pd);
        bf16x8 a3 = *(const bf16x8*)(pd + 32);

        // per-row broadcast metadata (rows quad*4+r)
        float radR[4]; int dstR[4]; float c0[4], c1c[4], c2[4];
#pragma unroll
        for (int r = 0; r < 4; ++r) {
            int er = quad * 4 + r;
            radR[r] = __shfl(rad, er);
            dstR[r] = __shfl(dn_, er);
            c0[r] = __shfl(xdx, er);
            c1c[r] = __shfl(xdy, er);
            c2[r] = __shfl(xdz, er);
        }

        // ---- GEMM1: K=128
        f32x4 acc[4];
#pragma unroll
        for (int nt = 0; nt < 4; ++nt) acc[nt] = (f32x4){0.f, 0.f, 0.f, 0.f};
        {
            const unsigned short* bBase = &w1T[l15 * SW + quad * 8];
#pragma unroll
            for (int nt = 0; nt < 4; ++nt) {
                const unsigned short* bb = bBase + nt * 16 * SW;
                acc[nt] = __builtin_amdgcn_mfma_f32_16x16x32_bf16(a0, *(const bf16x8*)(bb), acc[nt], 0, 0, 0);
                acc[nt] = __builtin_amdgcn_mfma_f32_16x16x32_bf16(a1, *(const bf16x8*)(bb + 32), acc[nt], 0, 0, 0);
                acc[nt] = __builtin_amdgcn_mfma_f32_16x16x32_bf16(a2, *(const bf16x8*)(bb + 64), acc[nt], 0, 0, 0);
                acc[nt] = __builtin_amdgcn_mfma_f32_16x16x32_bf16(a3, *(const bf16x8*)(bb + 96), acc[nt], 0, 0, 0);
            }
        }
        // epilogue1: bias + radial rank-1 + silu -> tW (bf16)
#pragma unroll
        for (int nt = 0; nt < 4; ++nt) {
            int col = nt * 16 + l15;
#pragma unroll
            for (int r = 0; r < 4; ++r) {
                float v = acc[nt][r] + eb1s[col] + radR[r] * w1l[col];
                tW[(quad * 4 + r) * ST + col] = f2bf(silu_f(v));
            }
        }
        // ---- GEMM2: K=64 (b2 in regs)
        f32x4 acc2[4];
#pragma unroll
        for (int nt = 0; nt < 4; ++nt) acc2[nt] = (f32x4){0.f, 0.f, 0.f, 0.f};
        {
            bf16x8 ax0 = *(const bf16x8*)&tW[l15 * ST + quad * 8];
            bf16x8 ax1 = *(const bf16x8*)&tW[l15 * ST + 32 + quad * 8];
#pragma unroll
            for (int nt = 0; nt < 4; ++nt) {
                acc2[nt] = __builtin_amdgcn_mfma_f32_16x16x32_bf16(ax0, b2[0][nt], acc2[nt], 0, 0, 0);
                acc2[nt] = __builtin_amdgcn_mfma_f32_16x16x32_bf16(ax1, b2[1][nt], acc2[nt], 0, 0, 0);
            }
        }
        // epilogue2: silu -> msg; atomic scatter + tW (bf16) for GEMM3
#pragma unroll
        for (int nt = 0; nt < 4; ++nt) {
            int col = nt * 16 + l15;
#pragma unroll
            for (int r = 0; r < 4; ++r) {
                float v = silu_f(acc2[nt][r] + eb2s[col]);
                atomicAdd(&h_neigh[(size_t)dstR[r] * 64 + col], v);
                tW[(quad * 4 + r) * ST + col] = f2bf(v);
            }
        }
        // ---- GEMM3: K=64 (b3 from LDS c1T)
        f32x4 acc3[4];
#pragma unroll
        for (int nt = 0; nt < 4; ++nt) acc3[nt] = (f32x4){0.f, 0.f, 0.f, 0.f};
        {
            bf16x8 ax0 = *(const bf16x8*)&tW[l15 * ST + quad * 8];
            bf16x8 ax1 = *(const bf16x8*)&tW[l15 * ST + 32 + quad * 8];
            const unsigned short* bBase = &c1T[l15 * ST + quad * 8];
#pragma unroll
            for (int nt = 0; nt < 4; ++nt) {
                const unsigned short* bb = bBase + nt * 16 * ST;
                acc3[nt] = __builtin_amdgcn_mfma_f32_16x16x32_bf16(ax0, *(const bf16x8*)(bb), acc3[nt], 0, 0, 0);
                acc3[nt] = __builtin_amdgcn_mfma_f32_16x16x32_bf16(ax1, *(const bf16x8*)(bb + 32), acc3[nt], 0, 0, 0);
            }
        }
        // coord head: silu, dot cw2, reduce over 16 lanes, scatter msg_x
        float part_[4] = {0.f, 0.f, 0.f, 0.f};
#pragma unroll
        for (int nt = 0; nt < 4; ++nt) {
            int col = nt * 16 + l15;
#pragma unroll
            for (int r = 0; r < 4; ++r)
                part_[r] += silu_f(acc3[nt][r] + cb1s[col]) * cw2s[col];
        }
#pragma unroll
        for (int r = 0; r < 4; ++r) {
            float p = part_[r];
            p += __shfl_xor(p, 1);
            p += __shfl_xor(p, 2);
            p += __shfl_xor(p, 4);
            p += __shfl_xor(p, 8);
            part_[r] = p;
        }
        if (l15 < 3) {
#pragma unroll
            for (int r = 0; r < 4; ++r) {
                float comp = (l15 == 0) ? c0[r] : (l15 == 1) ? c1c[r] : c2[r];
                atomicAdd(&x_sum[(size_t)dstR[r] * 3 + l15], part_[r] * comp);
            }
        }
    }
}

// ---------------------------------------------------------------------------
// Node kernel, barrier-free: each wave owns 16-node tiles.
// ---------------------------------------------------------------------------
__global__ __launch_bounds__(256, 4) void node_kernel(
    unsigned short* hbf,                 // in/out
    const float* __restrict__ h_neigh,
    const float* __restrict__ nw1,       // [128,64]
    const float* __restrict__ nb1,
    const float* __restrict__ nw2,       // [64,64]
    const float* __restrict__ nb2,
    const float* __restrict__ ln_g,
    const float* __restrict__ ln_b)
{
    __shared__ __align__(16) unsigned short w1T[64 * SW];
    __shared__ __align__(16) unsigned short tAll[4 * 16 * ST];
    __shared__ float nb1s[64], nb2s[64], gs[64], bs[64];

    const int tid  = threadIdx.x;
    const int wave = tid >> 6;
    const int lane = tid & 63;
    const int quad = lane >> 4;
    const int l15  = lane & 15;

    for (int i = tid; i < 64 * 128; i += 256) {
        int n = i & 63, k = i >> 6;
        w1T[n * SW + k] = f2bf(nw1[k * 64 + n]);
    }
    if (tid < 64) {
        nb1s[tid] = nb1[tid]; nb2s[tid] = nb2[tid];
        gs[tid] = ln_g[tid]; bs[tid] = ln_b[tid];
    }
    bf16x8 b2[2][4];
#pragma unroll
    for (int ks = 0; ks < 2; ++ks)
#pragma unroll
        for (int nt = 0; nt < 4; ++nt) {
#pragma unroll
            for (int j = 0; j < 8; ++j) {
                int k = ks * 32 + quad * 8 + j;
                ((unsigned short*)&b2[ks][nt])[j] = f2bf(nw2[k * 64 + nt * 16 + l15]);
            }
        }
    __syncthreads();

    unsigned short* tW = tAll + wave * 16 * ST;

    for (int t = blockIdx.x * 4 + wave; t < NN / 16; t += gridDim.x * 4) {
        const int n0 = t * 16;
        const int myRow = n0 + l15;
        // A-frags: cols 0..63 = h (bf16), 64..127 = h_neigh (fp32 -> bf16)
        const unsigned short* ph = hbf + (size_t)myRow * 64 + quad * 8;
        bf16x8 a0 = *(const bf16x8*)(ph);
        bf16x8 a1 = *(const bf16x8*)(ph + 32);
        bf16x8 a2, a3;
        {
            const float4* pn = (const float4*)(h_neigh + (size_t)myRow * 64 + quad * 8);
            float4 v0 = pn[0], v1 = pn[1];
            const float4* pm = (const float4*)(h_neigh + (size_t)myRow * 64 + 32 + quad * 8);
            float4 v2 = pm[0], v3 = pm[1];
            unsigned short* pa2 = (unsigned short*)&a2;
            unsigned short* pa3 = (unsigned short*)&a3;
            pa2[0] = f2bf(v0.x); pa2[1] = f2bf(v0.y); pa2[2] = f2bf(v0.z); pa2[3] = f2bf(v0.w);
            pa2[4] = f2bf(v1.x); pa2[5] = f2bf(v1.y); pa2[6] = f2bf(v1.z); pa2[7] = f2bf(v1.w);
            pa3[0] = f2bf(v2.x); pa3[1] = f2bf(v2.y); pa3[2] = f2bf(v2.z); pa3[3] = f2bf(v2.w);
            pa3[4] = f2bf(v3.x); pa3[5] = f2bf(v3.y); pa3[6] = f2bf(v3.z); pa3[7] = f2bf(v3.w);
        }
        f32x4 acc[4];
#pragma unroll
        for (int nt = 0; nt < 4; ++nt) acc[nt] = (f32x4){0.f, 0.f, 0.f, 0.f};
        {
            const unsigned short* bBase = &w1T[l15 * SW + quad * 8];
#pragma unroll
            for (int nt = 0; nt < 4; ++nt) {
                const unsigned short* bb = bBase + nt * 16 * SW;
                acc[nt] = __builtin_amdgcn_mfma_f32_16x16x32_bf16(a0, *(const bf16x8*)(bb), acc[nt], 0, 0, 0);
                acc[nt] = __builtin_amdgcn_mfma_f32_16x16x32_bf16(a1, *(const bf16x8*)(bb + 32), acc[nt], 0, 0, 0);
                acc[nt] = __builtin_amdgcn_mfma_f32_16x16x32_bf16(a2, *(const bf16x8*)(bb + 64), acc[nt], 0, 0, 0);
                acc[nt] = __builtin_amdgcn_mfma_f32_16x16x32_bf16(a3, *(const bf16x8*)(bb + 96), acc[nt], 0, 0, 0);
            }
        }
#pragma unroll
        for (int nt = 0; nt < 4; ++nt) {
            int col = nt * 16 + l15;
#pragma unroll
            for (int r = 0; r < 4; ++r) {
                float v = acc[nt][r] + nb1s[col];
                tW[(quad * 4 + r) * ST + col] = f2bf(silu_f(v));
            }
        }
        f32x4 acc2[4];
#pragma unroll
        for (int nt = 0; nt < 4; ++nt) acc2[nt] = (f32x4){0.f, 0.f, 0.f, 0.f};
        {
            bf16x8 ax0 = *(const bf16x8*)&tW[l15 * ST + quad * 8];
            bf16x8 ax1 = *(const bf16x8*)&tW[l15 * ST + 32 + quad * 8];
#pragma unroll
            for (int nt = 0; nt < 4; ++nt) {
                acc2[nt] = __builtin_amdgcn_mfma_f32_16x16x32_bf16(ax0, b2[0][nt], acc2[nt], 0, 0, 0);
                acc2[nt] = __builtin_amdgcn_mfma_f32_16x16x32_bf16(ax1, b2[1][nt], acc2[nt], 0, 0, 0);
            }
        }
        // gelu (exact) + LayerNorm (16-lane reductions)
        float vals[4][4];
        float sum[4] = {0.f, 0.f, 0.f, 0.f}, ss[4] = {0.f, 0.f, 0.f, 0.f};
#pragma unroll
        for (int nt = 0; nt < 4; ++nt) {
            int col = nt * 16 + l15;
#pragma unroll
            for (int r = 0; r < 4; ++r) {
                float v = acc2[nt][r] + nb2s[col];
                float g = 0.5f * v * (1.0f + erff(v * 0.70710678118654752f));
                vals[nt][r] = g;
                sum[r] += g;
                ss[r] += g * g;
            }
        }
#pragma unroll
        for (int r = 0; r < 4; ++r) {
            float s1 = sum[r], s2 = ss[r];
            s1 += __shfl_xor(s1, 1); s2 += __shfl_xor(s2, 1);
            s1 += __shfl_xor(s1, 2); s2 += __shfl_xor(s2, 2);
            s1 += __shfl_xor(s1, 4); s2 += __shfl_xor(s2, 4);
            s1 += __shfl_xor(s1, 8); s2 += __shfl_xor(s2, 8);
            sum[r] = s1; ss[r] = s2;
        }
#pragma unroll
        for (int r = 0; r < 4; ++r) {
            float mean = sum[r] * (1.0f / 64.0f);
            float var  = ss[r] * (1.0f / 64.0f) - mean * mean;
            float rstd = rsqrtf(var + 1e-5f);
            int n = n0 + quad * 4 + r;
#pragma unroll
            for (int nt = 0; nt < 4; ++nt) {
                int col = nt * 16 + l15;
                float y = (vals[nt][r] - mean) * rstd * gs[col] + bs[col];
                hbf[(size_t)n * 64 + col] = f2bf(y);
            }
        }
    }
}

__global__ void init_h(const float* __restrict__ nf, unsigned short* __restrict__ hbf) {
    int i = blockIdx.x * 256 + threadIdx.x;
    if (i < NN * 64) hbf[i] = f2bf(nf[i]);
}
__global__ void init_x(const float* __restrict__ xyz, float* __restrict__ xcur) {
    int i = blockIdx.x * 256 + threadIdx.x;
    if (i < NN * 3) xcur[i] = xyz[i];
}
__global__ void deg_kernel(const int* __restrict__ dst, float* __restrict__ deg) {
    int i = blockIdx.x * 256 + threadIdx.x;
    if (i < NE) atomicAdd(&deg[dst[i]], 1.0f);
}
__global__ void xupd(const float* __restrict__ x_sum, const float* __restrict__ deg,
                     float* __restrict__ xcur) {
    int n = blockIdx.x * 256 + threadIdx.x;
    if (n < NN) {
        float id = 1.0f / fmaxf(deg[n], 1.0f);
        xcur[n * 3 + 0] += x_sum[n * 3 + 0] * id;
        xcur[n * 3 + 1] += x_sum[n * 3 + 1] * id;
        xcur[n * 3 + 2] += x_sum[n * 3 + 2] * id;
    }
}
__global__ __launch_bounds__(256) void head_kernel(
    const unsigned short* __restrict__ hbf,
    const float* __restrict__ out_w,   // [64,32]
    const float* __restrict__ out_b,   // [32]
    float* __restrict__ out)
{
    __shared__ float w[64 * 32];
    __shared__ float b[32];
    int tid = threadIdx.x;
    for (int i = tid; i < 64 * 32; i += 256) w[i] = out_w[i];
    if (tid < 32) b[tid] = out_b[tid];
    __syncthreads();
    int co = tid & 31, nl = tid >> 5;
    for (int n = blockIdx.x * 8 + nl; n < NN; n += gridDim.x * 8) {
        float acc = b[co];
#pragma unroll 8
        for (int k = 0; k < 64; ++k)
            acc += bf2f(hbf[n * 64 + k]) * w[k * 32 + co];
        out[n * 32 + co] = acc;
    }
}

extern "C" void kernel_launch(void* const* d_in, const int* in_sizes, int n_in,
                              void* d_out, int out_size, void* d_ws, size_t ws_size,
                              hipStream_t stream)
{
    const float* node_feat = (const float*)d_in[0];
    const float* xyz   = (const float*)d_in[1];
    const int*   src   = (const int*)d_in[2];
    const int*   dst   = (const int*)d_in[3];
    const float* ew1   = (const float*)d_in[4];
    const float* eb1   = (const float*)d_in[5];
    const float* ew2   = (const float*)d_in[6];
    const float* eb2   = (const float*)d_in[7];
    const float* cw1   = (const float*)d_in[8];
    const float* cb1   = (const float*)d_in[9];
    const float* cw2   = (const float*)d_in[10];
    const float* nw1   = (const float*)d_in[11];
    const float* nb1   = (const float*)d_in[12];
    const float* nw2   = (const float*)d_in[13];
    const float* nb2   = (const float*)d_in[14];
    const float* ln_g  = (const float*)d_in[15];
    const float* ln_b  = (const float*)d_in[16];
    const float* out_w = (const float*)d_in[17];
    const float* out_b = (const float*)d_in[18];
    float* out = (float*)d_out;

    char* ws = (char*)d_ws;
    float* h_neigh = (float*)ws;               ws += (size_t)NN * 64 * 4;
    float* x_cur   = (float*)ws;               ws += (size_t)NN * 3 * 4;
    float* x_sum   = (float*)ws;               ws += (size_t)NN * 3 * 4;
    float* deg     = (float*)ws;               ws += (size_t)NN * 4;
    unsigned short* hbf = (unsigned short*)ws; ws += (size_t)NN * 64 * 2;

    hipMemsetAsync(deg, 0, (size_t)NN * 4, stream);
    init_h<<<(NN * 64 + 255) / 256, 256, 0, stream>>>(node_feat, hbf);
    init_x<<<(NN * 3 + 255) / 256, 256, 0, stream>>>(xyz, x_cur);
    deg_kernel<<<(NE + 255) / 256, 256, 0, stream>>>(dst, deg);

    for (int l = 0; l < 2; ++l) {
        hipMemsetAsync(h_neigh, 0, (size_t)NN * 64 * 4, stream);
        hipMemsetAsync(x_sum, 0, (size_t)NN * 3 * 4, stream);
        edge_kernel<<<2048, 256, 0, stream>>>(
            x_cur, hbf, src, dst,
            ew1 + l * 129 * 64, eb1 + l * 64,
            ew2 + l * 64 * 64, eb2 + l * 64,
            cw1 + l * 64 * 64, cb1 + l * 64, cw2 + l * 64,
            h_neigh, x_sum);
        if (l == 0)
            xupd<<<(NN + 255) / 256, 256, 0, stream>>>(x_sum, deg, x_cur);
        node_kernel<<<800, 256, 0, stream>>>(
            hbf, h_neigh,
            nw1 + l * 128 * 64, nb1 + l * 64,
            nw2 + l * 64 * 64, nb2 + l * 64,
            ln_g, ln_b);
    }
    head_kernel<<<1024, 256, 0, stream>>>(hbf, out_w, out_b, out);
}